// Round 11
// baseline (389.244 us; speedup 1.0000x reference)
//
#include <hip/hip_runtime.h>
#include <hip/hip_bf16.h>
#include <stdint.h>

typedef __attribute__((ext_vector_type(8))) short short8;
typedef __attribute__((ext_vector_type(4))) float floatx4;

// Q pre-scale: 0.125 (1/sqrt(K)) * log2(e), so exp(s/8) == exp2(q'.k)
#define QSCALE 0.18033688f

__device__ __forceinline__ unsigned short f2bf(float f) {
    unsigned int u = __float_as_uint(f);
    u += 0x7fffu + ((u >> 16) & 1u);
    return (unsigned short)(u >> 16);
}
__device__ __forceinline__ unsigned int pack2bf(float a, float b) {
    __hip_bfloat162 h = __float22bfloat162_rn(make_float2(a, b));
    return *reinterpret_cast<unsigned int*>(&h);
}

// async global->LDS, 16B per lane; LDS dst must be wave-uniform base + lane*16
__device__ __forceinline__ void async16(const void* g, void* l) {
    __builtin_amdgcn_global_load_lds(
        (const __attribute__((address_space(1))) unsigned int*)g,
        (__attribute__((address_space(3))) unsigned int*)l, 16, 0, 0);
}

// A-frag with k=0..3 real (P values), k=4..7 zero (bf16 0x0000).
__device__ __forceinline__ short8 padA(uint2 p) {
    union { uint4 u; short8 s; } t;
    t.u.x = p.x; t.u.y = p.y; t.u.z = 0u; t.u.w = 0u;
    return t.s;
}
// B-frag: duplicate one b64 of V into both k-halves (upper half hits A's
// zeros; duplication keeps B finite so no 0*NaN from over-reading).
__device__ __forceinline__ short8 dupB(uint2 v) {
    union { uint4 u; short8 s; } t;
    t.u.x = v.x; t.u.y = v.y; t.u.z = v.x; t.u.w = v.y;
    return t.s;
}

// ---------------------------------------------------------------------------
// cvt: fp32 -> bf16, 8 elements/thread
// ---------------------------------------------------------------------------
__global__ __launch_bounds__(256) void cvt_bf16(const float* __restrict__ src,
                                                unsigned short* __restrict__ dst, int n8) {
    int i = blockIdx.x * 256 + threadIdx.x;
    if (i >= n8) return;
    const float4 a = ((const float4*)src)[2 * i];
    const float4 b = ((const float4*)src)[2 * i + 1];
    ushort4 lo, hi;
    lo.x = f2bf(a.x); lo.y = f2bf(a.y); lo.z = f2bf(a.z); lo.w = f2bf(a.w);
    hi.x = f2bf(b.x); hi.y = f2bf(b.y); hi.z = f2bf(b.z); hi.w = f2bf(b.w);
    ((ushort4*)dst)[2 * i] = lo;
    ((ushort4*)dst)[2 * i + 1] = hi;
}

// ---------------------------------------------------------------------------
// tcvt: fp32 [R][C] -> bf16 [C][R]  (64x64 tiles via LDS)
// ---------------------------------------------------------------------------
__global__ __launch_bounds__(256) void tcvt(const float* __restrict__ src,
                                            unsigned short* __restrict__ dst, int R, int C) {
    __shared__ unsigned short t[64][72];
    const int tid = threadIdx.x;
    const int r0 = blockIdx.y * 64, c0 = blockIdx.x * 64;
    #pragma unroll
    for (int it = 0; it < 4; it++) {
        int idx = it * 256 + tid;
        int rr = idx >> 4, cc = (idx & 15) * 4;
        float4 v = *(const float4*)(src + (size_t)(r0 + rr) * C + c0 + cc);
        t[cc + 0][rr] = f2bf(v.x);
        t[cc + 1][rr] = f2bf(v.y);
        t[cc + 2][rr] = f2bf(v.z);
        t[cc + 3][rr] = f2bf(v.w);
    }
    __syncthreads();
    #pragma unroll
    for (int it = 0; it < 2; it++) {
        int idx = it * 256 + tid;
        int cc = idx >> 3, r8 = (idx & 7) * 8;
        short8 v = *(const short8*)&t[cc][r8];
        *(short8*)(dst + (size_t)(c0 + cc) * R + r0 + r8) = v;
    }
}

// ---------------------------------------------------------------------------
// vtrans: vb[bh][2048][64] -> vbt[bh][64][2048]  (64x64 tiles via LDS)
// ---------------------------------------------------------------------------
__global__ __launch_bounds__(256) void vtrans(const unsigned short* __restrict__ vb,
                                              unsigned short* __restrict__ vbt) {
    __shared__ unsigned short t[64][72];
    const int tid = threadIdx.x;
    const int bh = blockIdx.y, m0 = blockIdx.x * 64;
    const unsigned short* src = vb + ((size_t)bh * 2048 + m0) * 64;
    unsigned short* dst = vbt + ((size_t)bh << 17) + m0;
    union { short8 v; unsigned short u[8]; } tmp;
    #pragma unroll
    for (int it = 0; it < 2; it++) {
        int idx = it * 256 + tid;
        int m = idx >> 3, c8 = (idx & 7) * 8;
        tmp.v = *(const short8*)(src + (size_t)m * 64 + c8);
        #pragma unroll
        for (int j = 0; j < 8; j++) t[c8 + j][m] = tmp.u[j];
    }
    __syncthreads();
    #pragma unroll
    for (int it = 0; it < 2; it++) {
        int idx = it * 256 + tid;
        int k = idx >> 3, c8 = (idx & 7) * 8;
        short8 v = *(const short8*)&t[k][c8];
        *(short8*)(dst + (size_t)k * 2048 + c8) = v;
    }
}

// ---------------------------------------------------------------------------
// qkv_gemm v3 (R10): R5 inner loop; LDS-transpose epilogue with coalesced
// short8 stores (h = l>>7 makes head a row function).
// ---------------------------------------------------------------------------
__global__ __launch_bounds__(256) void qkv_gemm(
    const unsigned short* __restrict__ A, const unsigned short* __restrict__ Bt,
    unsigned short* __restrict__ qb, unsigned short* __restrict__ kb,
    unsigned short* __restrict__ vb)
{
    __shared__ __align__(16) unsigned short Smem[2 * 128 * 32];  // As | Bs, 16 KB
    unsigned short* As = Smem;
    unsigned short* Bs = Smem + 128 * 32;
    const int tid = threadIdx.x, wave = tid >> 6, lane = tid & 63;
    const int quad = lane >> 4, lr = lane & 15;
    const int wr = wave >> 1, wc = wave & 1;
    const int bm = blockIdx.y * 128, bn = blockIdx.x * 128;
    const int lrow = lane >> 2, lcol = (lane & 3) * 8;

    floatx4 acc[4][4];
    #pragma unroll
    for (int i = 0; i < 4; i++)
        #pragma unroll
        for (int j = 0; j < 4; j++) acc[i][j] = (floatx4)0.0f;

    for (int k0 = 0; k0 < 1024; k0 += 32) {
        #pragma unroll
        for (int t = 0; t < 2; t++) {
            const int rbase = wave * 32 + t * 16;       // wave-uniform
            const int r = rbase + lrow;
            async16(A  + (size_t)(bm + r) * 1024 + k0 + lcol, &As[rbase * 32]);
            async16(Bt + (size_t)(bn + r) * 1024 + k0 + lcol, &Bs[rbase * 32]);
        }
        __syncthreads();
        short8 af[4], bfr[4];
        #pragma unroll
        for (int i = 0; i < 4; i++)
            af[i] = *(const short8*)&As[(wr * 64 + i * 16 + lr) * 32 + quad * 8];
        #pragma unroll
        for (int j = 0; j < 4; j++)
            bfr[j] = *(const short8*)&Bs[(wc * 64 + j * 16 + lr) * 32 + quad * 8];
        #pragma unroll
        for (int i = 0; i < 4; i++)
            #pragma unroll
            for (int j = 0; j < 4; j++)
                acc[i][j] = __builtin_amdgcn_mfma_f32_16x16x32_bf16(af[i], bfr[j], acc[i][j], 0, 0, 0);
        __syncthreads();
    }

    // ---- epilogue: wave-private LDS transpose + coalesced short8 stores ----
    const int part = bn >> 10;
    unsigned short* __restrict__ dstb = (part == 0) ? qb : ((part == 1) ? kb : vb);
    const float sc = (part == 0) ? QSCALE : 1.0f;
    const int dblk = ((bn & 1023) >> 6) + wc;            // d>>6, wave-uniform
    unsigned short* ep = Smem + wave * 2048;             // 32 rows x 64 cols

    #pragma unroll
    for (int half = 0; half < 2; half++) {
        #pragma unroll
        for (int il = 0; il < 2; il++) {
            const int i = half * 2 + il;
            #pragma unroll
            for (int j = 0; j < 4; j++)
                #pragma unroll
                for (int r = 0; r < 4; r++)
                    ep[(il * 16 + quad * 4 + r) * 64 + j * 16 + lr] = f2bf(acc[i][j][r] * sc);
        }
        #pragma unroll
        for (int it = 0; it < 4; it++) {
            const int slot = it * 64 + lane;
            const int rr = slot >> 3, c8 = (slot & 7) * 8;
            short8 v = *(const short8*)&ep[rr * 64 + c8];
            const int row = bm + wr * 64 + half * 32 + rr;   // global x row
            const int bidx = row >> 11, lseq = row & 2047;
            const int h = lseq >> 7;
            const int l2 = (lseq & 127) * 16 + dblk;
            *(short8*)(dstb + (((size_t)(bidx * 16 + h) * 2048 + l2) << 6) + c8) = v;
        }
        // per-wave in-order DS pipe: half-1 writes can't pass half-0 reads
    }
}

__global__ __launch_bounds__(256) void out_gemm(
    const unsigned short* __restrict__ A, const unsigned short* __restrict__ Bt,
    float* __restrict__ C)
{
    __shared__ __align__(16) unsigned short As[128 * 32];
    __shared__ __align__(16) unsigned short Bs[128 * 32];
    const int tid = threadIdx.x, wave = tid >> 6, lane = tid & 63;
    const int quad = lane >> 4, lr = lane & 15;
    const int wr = wave >> 1, wc = wave & 1;
    const int bm = blockIdx.y * 128, bn = blockIdx.x * 128;
    const int lrow = lane >> 2, lcol = (lane & 3) * 8;

    floatx4 acc[4][4];
    #pragma unroll
    for (int i = 0; i < 4; i++)
        #pragma unroll
        for (int j = 0; j < 4; j++) acc[i][j] = (floatx4)0.0f;

    for (int k0 = 0; k0 < 1024; k0 += 32) {
        #pragma unroll
        for (int t = 0; t < 2; t++) {
            const int rbase = wave * 32 + t * 16;
            const int r = rbase + lrow;
            async16(A  + (size_t)(bm + r) * 1024 + k0 + lcol, &As[rbase * 32]);
            async16(Bt + (size_t)(bn + r) * 1024 + k0 + lcol, &Bs[rbase * 32]);
        }
        __syncthreads();
        short8 af[4], bfr[4];
        #pragma unroll
        for (int i = 0; i < 4; i++)
            af[i] = *(const short8*)&As[(wr * 64 + i * 16 + lr) * 32 + quad * 8];
        #pragma unroll
        for (int j = 0; j < 4; j++)
            bfr[j] = *(const short8*)&Bs[(wc * 64 + j * 16 + lr) * 32 + quad * 8];
        #pragma unroll
        for (int i = 0; i < 4; i++)
            #pragma unroll
            for (int j = 0; j < 4; j++)
                acc[i][j] = __builtin_amdgcn_mfma_f32_16x16x32_bf16(af[i], bfr[j], acc[i][j], 0, 0, 0);
        __syncthreads();
    }
    #pragma unroll
    for (int i = 0; i < 4; i++)
        #pragma unroll
        for (int j = 0; j < 4; j++)
            #pragma unroll
            for (int r = 0; r < 4; r++) {
                int row = bm + wr * 64 + i * 16 + quad * 4 + r;
                int col = bn + wc * 64 + j * 16 + lr;
                C[(size_t)row * 1024 + col] = acc[i][j][r];
            }
}

// ---------------------------------------------------------------------------
// attn_denom v2 (R5-proven): Q/K double-buffered in LDS, staged with
// global_load_lds (un-sinkable; pre-XOR'd source involution per rule 21),
// one barrier per head. LDS 32 KB -> 5 blocks/CU.
// ---------------------------------------------------------------------------
__global__ __launch_bounds__(256, 5) void attn_denom(
    const unsigned short* __restrict__ qb, const unsigned short* __restrict__ kb,
    unsigned short* __restrict__ drpT)
{
    __shared__ __align__(16) unsigned short Qs[2][64 * 64];  // 16 KB
    __shared__ __align__(16) unsigned short Ks[2][64 * 64];  // 16 KB
    const int tid = threadIdx.x, wave = tid >> 6, lane = tid & 63;
    const int quad = lane >> 4, lr = lane & 15;
    const int e7 = lr & 7;
    const int M0 = blockIdx.x * 64, L0 = blockIdx.y * 64, b = blockIdx.z;

    const int klr = lane >> 3;
    const int ksw8 = ((lane & 7) ^ klr) * 8;
    const size_t hb0 = ((size_t)(b * 16)) << 17;
    const unsigned short* qsrc0 = qb + hb0 + (size_t)(L0 + wave * 8 + klr) * 64 + ksw8;
    const unsigned short* ksrc0 = kb + hb0 + (size_t)(M0 + wave * 8 + klr) * 64 + ksw8;

    floatx4 e[4];
    #pragma unroll
    for (int i = 0; i < 4; i++) e[i] = (floatx4)0.0f;

    async16(qsrc0,           &Qs[0][(wave * 8) * 64]);
    async16(qsrc0 + 32 * 64, &Qs[0][(32 + wave * 8) * 64]);
    async16(ksrc0,           &Ks[0][(wave * 8) * 64]);
    async16(ksrc0 + 32 * 64, &Ks[0][(32 + wave * 8) * 64]);
    __syncthreads();

    for (int h = 0; h < 16; h++) {
        const int cur = h & 1, nxt = cur ^ 1;
        if (h < 15) {
            const unsigned short* qs = qsrc0 + ((size_t)(h + 1) << 17);
            const unsigned short* ks = ksrc0 + ((size_t)(h + 1) << 17);
            async16(qs,           &Qs[nxt][(wave * 8) * 64]);
            async16(qs + 32 * 64, &Qs[nxt][(32 + wave * 8) * 64]);
            async16(ks,           &Ks[nxt][(wave * 8) * 64]);
            async16(ks + 32 * 64, &Ks[nxt][(32 + wave * 8) * 64]);
        }
        const unsigned short* qsp = &Qs[cur][0];
        const unsigned short* ksp = &Ks[cur][0];
        const int rq = wave * 16 + lr;
        short8 qf0 = *(const short8*)&qsp[rq * 64 + (quad ^ e7) * 8];
        short8 qf1 = *(const short8*)&qsp[rq * 64 + ((4 + quad) ^ e7) * 8];
        #pragma unroll
        for (int mt = 0; mt < 4; mt++) {
            const int rk = mt * 16 + lr;
            short8 kf0 = *(const short8*)&ksp[rk * 64 + (quad ^ e7) * 8];
            short8 kf1 = *(const short8*)&ksp[rk * 64 + ((4 + quad) ^ e7) * 8];
            floatx4 s = (floatx4)0.0f;
            __builtin_amdgcn_s_setprio(1);
            s = __builtin_amdgcn_mfma_f32_16x16x32_bf16(kf0, qf0, s, 0, 0, 0);
            s = __builtin_amdgcn_mfma_f32_16x16x32_bf16(kf1, qf1, s, 0, 0, 0);
            __builtin_amdgcn_s_setprio(0);
            e[mt][0] += __builtin_amdgcn_exp2f(s[0]);
            e[mt][1] += __builtin_amdgcn_exp2f(s[1]);
            e[mt][2] += __builtin_amdgcn_exp2f(s[2]);
            e[mt][3] += __builtin_amdgcn_exp2f(s[3]);
        }
        if (h < 15) __syncthreads();
    }
    #pragma unroll
    for (int mt = 0; mt < 4; mt++) {
        float r0 = __builtin_amdgcn_rcpf(e[mt][0]);
        float r1 = __builtin_amdgcn_rcpf(e[mt][1]);
        float r2 = __builtin_amdgcn_rcpf(e[mt][2]);
        float r3 = __builtin_amdgcn_rcpf(e[mt][3]);
        uint2 o;
        o.x = pack2bf(r0, r1);
        o.y = pack2bf(r2, r3);
        int mtg = (M0 >> 4) + mt;
        int ltg = (L0 >> 4) + wave;
        *(uint2*)(drpT + ((((size_t)b * 128 + mtg) * 128 + ltg) << 8) + lane * 4) = o;
    }
}

// ---------------------------------------------------------------------------
// attn_pv v8: waves split m (not l). Wave w owns m-rows [16w,16w+16) of each
// 64-m step and computes S^T for 64 l x 16 m -> P stays ENTIRELY in registers:
// S^T acc (m=q*4+r, l=lane&15) IS the 16x16x32 A-frag layout (row=lane&15,
// k=q*8+j) with k=4..7 zero-padded (padA); B = one b64 of V duplicated into
// both halves (dupB; upper half multiplies A's zeros). Eliminates Ps (8 KB +
// 12 LDS-ops/wave/step) and cuts K reads 8->2 b128, V reads 8 b128 -> 4 b64:
// LDS traffic 112 KB -> 32 KB per block-step (R6 showed pv's critical path is
// LDS-read-sensitive). oacc is partial over the wave's m-quarter; one LDS
// reduction at kernel end (aliases dead KV). 3-buffer K/V rotation + barrier
// schedule verbatim from R5. Block = (b,h,64 l), grid 2048, XCD-swizzled.
// ---------------------------------------------------------------------------
__global__ __launch_bounds__(256, 3) void attn_pv(
    const unsigned short* __restrict__ qb, const unsigned short* __restrict__ kb,
    const unsigned short* __restrict__ vbt, const unsigned short* __restrict__ drpT,
    unsigned short* __restrict__ cb)
{
    __shared__ __align__(16) unsigned short KV[3][64 * 64];  // 24 KB rotating K/V
    const int tid = threadIdx.x, wave = tid >> 6, lane = tid & 63;
    const int quad = lane >> 4, lr = lane & 15;
    const int e7 = lr & 7;
    // bijective XCD swizzle over 2048 blocks
    const int flat = blockIdx.x;
    const int swz = (flat & 7) * 256 + (flat >> 3);
    const int Lt = swz & 31;
    const int h = (swz >> 5) & 15;
    const int b = swz >> 9;
    const int L0 = Lt * 64;
    const size_t head = (size_t)(b * 16 + h);
    const unsigned short* qbase = qb + (head << 17);
    const unsigned short* kbase = kb + (head << 17);
    const unsigned short* vtb   = vbt + (head << 17);        // [64][2048]
    // drp tile (mtg = t*4 + wave, ltg = (L0>>4) + lt): per-t stride 4*128*256 = <<17
    const unsigned short* dbase = drpT + (((size_t)b * 128 + wave) * 128 + (L0 >> 4)) * 256 + lane * 4;

    // staging lanes (rule-21 involution, verbatim from R5)
    const int klr = lane >> 3;
    const int ksw = (lane & 7) ^ klr;
    const unsigned short* ksrc0 = kbase + (size_t)(wave * 8 + klr) * 64 + ksw * 8;
    const unsigned short* vsrc0 = vtb + (size_t)(wave * 8 + klr) * 2048 + ksw * 8;

    // Q B-frags for all 4 l-tiles of this block (rows L0 + lt*16 + lr)
    short8 qf[4][2];
    #pragma unroll
    for (int lt = 0; lt < 4; lt++) {
        const unsigned short* qr = qbase + (size_t)(L0 + lt * 16 + lr) * 64;
        qf[lt][0] = *(const short8*)(qr + quad * 8);
        qf[lt][1] = *(const short8*)(qr + 32 + quad * 8);
    }

    floatx4 oacc[4][4];   // [l-tile][n-tile], partial over this wave's m-quarter
    #pragma unroll
    for (int i = 0; i < 4; i++)
        #pragma unroll
        for (int j = 0; j < 4; j++) oacc[i][j] = (floatx4)0.0f;

    // prologue: stage K(0)->KV[0], V(0)->KV[1]; load drp(0)
    async16(ksrc0,             &KV[0][(wave * 8) * 64]);
    async16(ksrc0 + 32 * 64,   &KV[0][(32 + wave * 8) * 64]);
    async16(vsrc0,             &KV[1][(wave * 8) * 64]);
    async16(vsrc0 + 32 * 2048, &KV[1][(32 + wave * 8) * 64]);
    uint2 du[4];
    #pragma unroll
    for (int lt = 0; lt < 4; lt++)
        du[lt] = *(const uint2*)(dbase + (lt << 8));
    __syncthreads();

    // V b64 element offset within a row: logical 8-block = wave*2 + (quad>>1),
    // physical = ^e7; inner 4-element offset = (quad&1)*4
    const int vblk = (((wave * 2 + (quad >> 1)) ^ e7) << 3) + ((quad & 1) << 2);

    int kcur = 0, vcur = 1, sp = 2;
    for (int t = 0; t < 32; t++) {
        const int M0 = t * 64;
        // ---- issue async K(t+1) into the spare buffer (cover = S phase) ----
        if (t < 31) {
            const unsigned short* ks = ksrc0 + (size_t)(M0 + 64) * 64;
            async16(ks,           &KV[sp][(wave * 8) * 64]);
            async16(ks + 32 * 64, &KV[sp][(32 + wave * 8) * 64]);
        }
        // ---- S phase: this wave's 16 m-rows x 64 l; P -> registers ----
        const unsigned short* ksp = &KV[kcur][0];
        const int rk = wave * 16 + lr;
        short8 kf0 = *(const short8*)&ksp[rk * 64 + (quad ^ e7) * 8];
        short8 kf1 = *(const short8*)&ksp[rk * 64 + ((4 + quad) ^ e7) * 8];
        uint2 pa[4];
        #pragma unroll
        for (int lt = 0; lt < 4; lt++) {
            uint2 duv = du[lt];
            floatx4 s = (floatx4)0.0f;
            __builtin_amdgcn_s_setprio(1);
            s = __builtin_amdgcn_mfma_f32_16x16x32_bf16(kf0, qf[lt][0], s, 0, 0, 0);
            s = __builtin_amdgcn_mfma_f32_16x16x32_bf16(kf1, qf[lt][1], s, 0, 0, 0);
            __builtin_amdgcn_s_setprio(0);
            float r0 = __uint_as_float(duv.x << 16);
            float r1 = __uint_as_float(duv.x & 0xffff0000u);
            float r2 = __uint_as_float(duv.y << 16);
            float r3 = __uint_as_float(duv.y & 0xffff0000u);
            float p0 = __builtin_amdgcn_exp2f(s[0]) * r0;
            float p1 = __builtin_amdgcn_exp2f(s[1]) * r1;
            float p2 = __builtin_amdgcn_exp2f(s[2]) * r2;
            float p3 = __builtin_amdgcn_exp2f(s[3]) * r3;
            pa[lt].x = pack2bf(p0, p1);
            pa[lt].y = pack2bf(p2, p3);
        }
        // ---- barrier #1: K(t) dead, K(t+1) landed; stage V(t+1) into kcur,
        //      reload drp(t+1) (covered by PV) ----
        if (t < 31) {
            __syncthreads();
            const unsigned short* vs = vsrc0 + (M0 + 64);
            async16(vs,             &KV[kcur][(wave * 8) * 64]);
            async16(vs + 32 * 2048, &KV[kcur][(32 + wave * 8) * 64]);
            #pragma unroll
            for (int lt = 0; lt < 4; lt++)
                du[lt] = *(const uint2*)(dbase + ((size_t)(t + 1) << 17) + (lt << 8));
        }
        __builtin_amdgcn_sched_barrier(0);
        // ---- PV phase: register P A-frags x V b64 B-frags ----
        const unsigned short* vsp = &KV[vcur][0];
        #pragma unroll
        for (int nt = 0; nt < 4; nt++) {
            uint2 v = *(const uint2*)&vsp[(nt * 16 + lr) * 64 + vblk];
            short8 vf = dupB(v);
            __builtin_amdgcn_s_setprio(1);
            #pragma unroll
            for (int lt = 0; lt < 4; lt++)
                oacc[lt][nt] = __builtin_amdgcn_mfma_f32_16x16x32_bf16(
                    padA(pa[lt]), vf, oacc[lt][nt], 0, 0, 0);
            __builtin_amdgcn_s_setprio(0);
        }
        // ---- barrier #2: V(t) dead, V(t+1) landed. Rotate. ----
        if (t < 31) {
            __syncthreads();
            const int ok = kcur;
            kcur = sp;
            sp = vcur;
            vcur = ok;
        }
    }

    // ---- cross-wave reduction of partial O (4 chunks of 16 l-rows) ----
    __syncthreads();                       // all waves done with KV buffers
    float* red = (float*)&KV[0][0];        // [4 waves][16 rows][64 cols] = 16 KB
    #pragma unroll
    for (int lt = 0; lt < 4; lt++) {
        #pragma unroll
        for (int nt = 0; nt < 4; nt++)
            #pragma unroll
            for (int r = 0; r < 4; r++)
                red[(wave * 16 + quad * 4 + r) * 64 + nt * 16 + lr] = oacc[lt][nt][r];
        __syncthreads();
        #pragma unroll
        for (int rr = 0; rr < 4; rr++) {
            const int row = wave * 4 + rr;
            float s4 = red[(0 * 16 + row) * 64 + lane] + red[(1 * 16 + row) * 64 + lane]
                     + red[(2 * 16 + row) * 64 + lane] + red[(3 * 16 + row) * 64 + lane];
            cb[(size_t)(b * 2048 + L0 + lt * 16 + row) * 1024 + h * 64 + lane] = f2bf(s4);
        }
        __syncthreads();
    }
}

extern "C" void kernel_launch(void* const* d_in, const int* in_sizes, int n_in,
                              void* d_out, int out_size, void* d_ws, size_t ws_size,
                              hipStream_t stream) {
    const float* x    = (const float*)d_in[0];   // [4,2048,1024]
    const float* wqkv = (const float*)d_in[1];   // [1024,3072]
    const float* wo   = (const float*)d_in[2];   // [1024,1024]
    float* out = (float*)d_out;                  // [4,2048,1024] fp32

    // workspace: 100,663,296 bytes with overlays
    unsigned short* W = (unsigned short*)d_ws;
    unsigned short* qb   = W;                    // [4,16,2048,64] pre-scaled Q
    unsigned short* kb   = W + 8388608;          // [4,16,2048,64]
    unsigned short* vbt  = W + 16777216;         // [4,16,64,2048] V^T
    unsigned short* drpT = W + 25165824;         // [4][128mt][128lt][256] recip denom
    unsigned short* cb   = W + 41943040;         // [8192,1024] concat
    // overlays (lifetime-disjoint):
    unsigned short* xb    = drpT;                // bf16 x   (dead before denom)
    unsigned short* wqkvT = drpT + 8388608;      // bf16 wqkv^T [3072][1024]
    unsigned short* vb    = cb;                  // V row-major (dead before pv)
    unsigned short* woT   = drpT;                // bf16 wo^T [1024][1024] (after pv)

    cvt_bf16  <<<4096, 256, 0, stream>>>(x, xb, 1048576);
    tcvt      <<<dim3(48, 16), 256, 0, stream>>>(wqkv, wqkvT, 1024, 3072);
    qkv_gemm  <<<dim3(24, 64), 256, 0, stream>>>(xb, wqkvT, qb, kb, vb);
    vtrans    <<<dim3(32, 64), 256, 0, stream>>>(vb, vbt);
    attn_denom<<<dim3(32, 32, 4), 256, 0, stream>>>(qb, kb, drpT);
    attn_pv   <<<2048, 256, 0, stream>>>(qb, kb, vbt, drpT, cb);
    tcvt      <<<dim3(16, 16), 256, 0, stream>>>(wo, woT, 1024, 1024);
    out_gemm  <<<dim3(8, 64), 256, 0, stream>>>(cb, woT, out);
}